// Round 3
// baseline (322.331 us; speedup 1.0000x reference)
//
#include <hip/hip_runtime.h>

// Problem constants (fixed by reference: x is (2, 4, 128, 128, 128) fp32)
#define NBATCH 2
#define NDIM   128
#define NP     (128 * 128 * 128)        // particles per batch = mesh cells (2^21)
#define DIS_NORM 3.072f                  // 6 * 512 / 1000

// Tiling: 16^3 origin tiles; LDS window halo LO=5 below, HI=6 above.
// WIN=27 -> 19683 float cells, native ds_add_f32 deposits (8 atomics/particle).
// ~81.3 KB LDS total -> 2 blocks/CU in scatter.
#define TS   16
#define LO   5
#define HI   6
#define WIN  (TS + LO + HI)              // 27
#define WIN2 (WIN * WIN)                 // 729
#define WINF (WIN * WIN * WIN)           // 19683
#define WINP ((WINF + 3) & ~3)           // 19684, float4-padded
#define TPB  8
#define NTILE (TPB * TPB * TPB)          // 512 tiles per batch
#define NTHR 512

// Spill queue: expected ~98 slow particles/block (2.4% of 4096); 1280 is >>13 sigma.
#define QCAP 1280

// Destination-major inbox: each dest tile owns a contiguous slab of 27
// pieces (source offset o = src - dest; extents by j = 1 - m: {6,16,5}),
// piece bases padded to 4 floats. Slab = 19692 -> 19696 floats.
#define SLAB 19696

// ws layout (floats): [0..1024) partial sums; [1024..) per-tile slabs
#define SUMS_OFF 0
#define SLABS_OFF 1024
#define WS_FLOATS ((size_t)SLABS_OFF + (size_t)NBATCH * NTILE * SLAB)
#define WS_NEEDED_BYTES (WS_FLOATS * sizeof(float))

__device__ __constant__ int BASE27[27] = {
    0,216,792,972,1548,3084,3564,3744,4224,
    4376,4952,6488,6968,8504,12600,13880,14360,15640,
    16040,16220,16700,16852,17332,18612,19012,19164,19564};

// ---------------------------------------------------------------------------
// Kernel 1: prep. Planes 0..5: per-block partial sums of displacement
// channels. Plane 6: zero d_out (spill deposits land there atomically).
// ---------------------------------------------------------------------------
__global__ __launch_bounds__(256) void prep_kernel(const float* __restrict__ x,
                                                   float* __restrict__ ws,
                                                   float* __restrict__ out) {
    const int plane = blockIdx.y;
    if (plane < 6) {
        const int n = plane / 3, c = plane % 3;
        const float4* xp = (const float4*)(x + ((size_t)n * 4 + c) * NP);
        float s = 0.0f;
        for (int i = blockIdx.x * 256 + threadIdx.x; i < NP / 4; i += 128 * 256) {
            float4 v = xp[i];
            s += (v.x + v.y) + (v.z + v.w);
        }
        #pragma unroll
        for (int off = 32; off > 0; off >>= 1) s += __shfl_down(s, off, 64);
        __shared__ float wsum[4];
        if ((threadIdx.x & 63) == 0) wsum[threadIdx.x >> 6] = s;
        __syncthreads();
        if (threadIdx.x == 0)
            ws[SUMS_OFF + plane * 128 + blockIdx.x] =
                (wsum[0] + wsum[1]) + (wsum[2] + wsum[3]);
    } else {
        float4* o4 = (float4*)out;
        const float4 z = make_float4(0.f, 0.f, 0.f, 0.f);
        for (int i = blockIdx.x * 256 + threadIdx.x; i < NBATCH * NP / 4; i += 128 * 256)
            o4[i] = z;
    }
}

// Fallback-path means (serial 128-sum; only used by scatter_direct_kernel).
__device__ __forceinline__ void load_means128(const float* __restrict__ ws, int n,
                                              float& m0, float& m1, float& m2) {
    float s0 = 0.f, s1 = 0.f, s2 = 0.f;
    const float* p0 = ws + SUMS_OFF + (n * 3 + 0) * 128;
    const float* p1 = ws + SUMS_OFF + (n * 3 + 1) * 128;
    const float* p2 = ws + SUMS_OFF + (n * 3 + 2) * 128;
    #pragma unroll 4
    for (int b = 0; b < 128; ++b) { s0 += p0[b]; s1 += p1[b]; s2 += p2[b]; }
    const float inv_np = 1.0f / (float)NP;
    m0 = s0 * inv_np; m1 = s1 * inv_np; m2 = s2 * inv_np;
}

// General-case deposit (any position): window cells -> ds_add_f32 LDS atomics,
// out-of-window but in-mesh -> global spill atomics.
__device__ __forceinline__ void slow_deposit(float* __restrict__ winF,
                                             float* __restrict__ sp,
                                             float pd, float ph, float pw, float v,
                                             int od, int oh, int ow) {
    const float fd = floorf(pd), fh = floorf(ph), fw = floorf(pw);
    const int id = (int)fd, ih = (int)fh, iw = (int)fw;
    const float rd = pd - fd, rh = ph - fh, rw = pw - fw;
    const int wd = id - od, wh = ih - oh, ww = iw - ow;
    const float wd2[2] = {1.0f - rd, rd};
    const float wh2[2] = {1.0f - rh, rh};
    const float ww2[2] = {1.0f - rw, rw};
    #pragma unroll
    for (int dd = 0; dd < 2; ++dd) {
        const int td = id + dd, wdc = wd + dd;
        const bool dW = (unsigned)wdc < WIN, dM = (unsigned)td < NDIM;
        if (!dM && !dW) continue;
        #pragma unroll
        for (int hh = 0; hh < 2; ++hh) {
            const int th = ih + hh, whc = wh + hh;
            const bool hW = (unsigned)whc < WIN, hM = (unsigned)th < NDIM;
            const float vdh = v * wd2[dd] * wh2[hh];
            #pragma unroll
            for (int wi = 0; wi < 2; ++wi) {
                const int tw = iw + wi, wwc = ww + wi;
                const bool wW = (unsigned)wwc < WIN, wM = (unsigned)tw < NDIM;
                const float dep = vdh * ww2[wi];
                if (dW && hW && wW) {
                    atomicAdd(&winF[(wdc * WIN + whc) * WIN + wwc], dep);
                } else if (dM && hM && wM) {
                    atomicAdd(sp + ((size_t)td * NDIM + th) * NDIM + tw, dep);
                }
            }
        }
    }
}

// ---------------------------------------------------------------------------
// Kernel 2: tiled CIC scatter + cheap destination-major flush.
// Window is plain fp32 with native LDS float atomics (no fixed-point decode
// pass). Slow-path particles (~2.4%) are queued and drained after the main
// loop. Block means come from a 3-wave shuffle reduction (not 128 serial
// loads per thread).
// ---------------------------------------------------------------------------
__global__ __launch_bounds__(NTHR, 4) void scatter_tile_kernel(
        const float* __restrict__ x, const float* __restrict__ ws,
        float* __restrict__ slabs, float* __restrict__ out) {
    const int blk = blockIdx.x;              // 0 .. 2*NTILE-1
    const int n = blk >> 9;
    const int t = blk & (NTILE - 1);
    const int tx = t & 7, ty = (t >> 3) & 7, tz = t >> 6;

    __shared__ float winF[WINP];             // 78736 B
    __shared__ float smean[3];
    __shared__ int qcount;
    __shared__ unsigned short queue[QCAP];   // 2560 B
    {
        float4* z4 = (float4*)winF;
        const float4 z = make_float4(0.f, 0.f, 0.f, 0.f);
        for (int i = threadIdx.x; i < WINP / 4; i += NTHR) z4[i] = z;
        if (threadIdx.x == 0) qcount = 0;
    }
    // means: waves 0..2 each reduce one channel's 128 partials (deterministic)
    if (threadIdx.x < 192) {
        const int c = threadIdx.x >> 6;      // 0..2
        const int l = threadIdx.x & 63;
        const float* p = ws + SUMS_OFF + (n * 3 + c) * 128;
        float s = p[l] + p[l + 64];
        #pragma unroll
        for (int off = 32; off > 0; off >>= 1) s += __shfl_down(s, off, 64);
        if (l == 0) smean[c] = s * (1.0f / (float)NP);
    }
    __syncthreads();
    const float m0 = smean[0], m1 = smean[1], m2 = smean[2];

    // ---- deposit phase: 512 threads x 8 particles ----
    const int i0 = threadIdx.x * 8;
    const int lw0 = i0 & 15;
    const int lh  = (i0 >> 4) & 15;
    const int ld  = i0 >> 8;
    const int gd = tz * TS + ld, gh = ty * TS + lh, gw0 = tx * TS + lw0;
    const size_t prow = ((size_t)gd * NDIM + gh) * NDIM + gw0;

    const float4* x4 = (const float4*)(x + (size_t)n * 4 * NP);
    const size_t q = prow >> 2;
    const size_t s4 = NP / 4;
    float4 a0 = x4[0 * s4 + q], a1 = x4[0 * s4 + q + 1];
    float4 b0 = x4[1 * s4 + q], b1 = x4[1 * s4 + q + 1];
    float4 c0 = x4[2 * s4 + q], c1 = x4[2 * s4 + q + 1];
    float4 e0 = x4[3 * s4 + q], e1 = x4[3 * s4 + q + 1];
    const float D0[8] = {a0.x, a0.y, a0.z, a0.w, a1.x, a1.y, a1.z, a1.w};
    const float D1[8] = {b0.x, b0.y, b0.z, b0.w, b1.x, b1.y, b1.z, b1.w};
    const float D2[8] = {c0.x, c0.y, c0.z, c0.w, c1.x, c1.y, c1.z, c1.w};
    const float VV[8] = {e0.x, e0.y, e0.z, e0.w, e1.x, e1.y, e1.z, e1.w};

    const int od = tz * TS - LO, oh = ty * TS - LO, ow = tx * TS - LO;
    float* sp = out + (size_t)n * NP;

    #pragma unroll
    for (int k = 0; k < 8; ++k) {
        const float pd = (D0[k] - m0) * DIS_NORM + (float)gd + 0.5f;
        const float ph = (D1[k] - m1) * DIS_NORM + (float)gh + 0.5f;
        const float pw = (D2[k] - m2) * DIS_NORM + (float)(gw0 + k) + 0.5f;
        const float v = VV[k];

        const float fd = floorf(pd), fh = floorf(ph), fw = floorf(pw);
        const int id = (int)fd, ih = (int)fh, iw = (int)fw;
        const float rd = pd - fd, rh = ph - fh, rw = pw - fw;

        const int wd = id - od, wh = ih - oh, ww = iw - ow;
        if ((unsigned)wd <= WIN - 2 && (unsigned)wh <= WIN - 2 &&
            (unsigned)ww <= WIN - 2) {
            const int b00 = (wd * WIN + wh) * WIN + ww;
            const float sd0 = v * (1.0f - rd), sd1 = v * rd;
            const float h0 = 1.0f - rh, h1 = rh;
            const float q0 = 1.0f - rw, q1 = rw;
            const float w00 = sd0 * h0, w01 = sd0 * h1;
            const float w10 = sd1 * h0, w11 = sd1 * h1;
            atomicAdd(&winF[b00],                  w00 * q0);
            atomicAdd(&winF[b00 + 1],              w00 * q1);
            atomicAdd(&winF[b00 + WIN],            w01 * q0);
            atomicAdd(&winF[b00 + WIN + 1],        w01 * q1);
            atomicAdd(&winF[b00 + WIN2],           w10 * q0);
            atomicAdd(&winF[b00 + WIN2 + 1],       w10 * q1);
            atomicAdd(&winF[b00 + WIN2 + WIN],     w11 * q0);
            atomicAdd(&winF[b00 + WIN2 + WIN + 1], w11 * q1);
        } else {
            const int qi = atomicAdd(&qcount, 1);
            if (qi < QCAP) {
                queue[qi] = (unsigned short)(i0 + k);
            } else {
                // overflow fallback (statistically unreachable): do it inline
                slow_deposit(winF, sp, pd, ph, pw, v, od, oh, ow);
            }
        }
    }

    __syncthreads();

    // ---- drain spill queue: all lanes active, ~98 entries/block ----
    {
        const int nq = min(qcount, QCAP);
        const float* xb = x + (size_t)n * 4 * NP;
        for (int qi = threadIdx.x; qi < nq; qi += NTHR) {
            const int p = queue[qi];
            const int lw = p & 15, lhq = (p >> 4) & 15, ldq = p >> 8;
            const int gdq = tz * TS + ldq, ghq = ty * TS + lhq, gwq = tx * TS + lw;
            const size_t pr = ((size_t)gdq * NDIM + ghq) * NDIM + gwq;
            const float pd = (xb[pr] - m0) * DIS_NORM + (float)gdq + 0.5f;
            const float ph = (xb[(size_t)NP + pr] - m1) * DIS_NORM + (float)ghq + 0.5f;
            const float pw = (xb[2 * (size_t)NP + pr] - m2) * DIS_NORM + (float)gwq + 0.5f;
            const float v = xb[3 * (size_t)NP + pr];
            slow_deposit(winF, sp, pd, ph, pw, v, od, oh, ow);
        }
    }
    __syncthreads();

    // ---- flush: one thread per (lz,ly) row; 3 fixed x-segments ----
    const int EXTY[3] = {6, 16, 5};
    const int nbase = n << 9;
    for (int r = threadIdx.x; r < WIN2; r += NTHR) {
        const int lz = r / WIN;
        const int ly = r - lz * WIN;
        int mz, pz;
        if (lz < LO) { mz = -1; pz = lz; }
        else if (lz < LO + TS) { mz = 0; pz = lz - LO; }
        else { mz = 1; pz = lz - LO - TS; }
        int my, py;
        if (ly < LO) { my = -1; py = ly; }
        else if (ly < LO + TS) { my = 0; py = ly - LO; }
        else { my = 1; py = ly - LO - TS; }
        const int dtz = tz + mz, dty = ty + my;
        if ((unsigned)dtz >= TPB || (unsigned)dty >= TPB) continue;

        const int jz = 1 - mz, jy = 1 - my;
        const int ey = EXTY[jy];
        const int rowoff = pz * ey + py;
        const int pobase = jz * 9 + jy * 3;
        const float* src = winF + r * WIN;
        const int slabRow = nbase + (dtz * 8 + dty) * 8;

        // seg A: jx=2 (dest tile tx-1), lx 0..4, ex=5
        if (tx > 0) {
            float* d = slabs + (size_t)(slabRow + tx - 1) * SLAB
                     + BASE27[pobase + 2] + rowoff * 5;
            #pragma unroll
            for (int k = 0; k < 5; ++k) d[k] = src[k];
        }
        // seg B: jx=1 (own tile), lx 5..20, ex=16, aligned float4 stores
        {
            float* d = slabs + (size_t)(slabRow + tx) * SLAB
                     + BASE27[pobase + 1] + rowoff * 16;
            #pragma unroll
            for (int k = 0; k < 4; ++k) {
                float4 v;
                v.x = src[5 + 4 * k]; v.y = src[6 + 4 * k];
                v.z = src[7 + 4 * k]; v.w = src[8 + 4 * k];
                ((float4*)d)[k] = v;
            }
        }
        // seg C: jx=0 (dest tile tx+1), lx 21..26, ex=6
        if (tx < TPB - 1) {
            float* d = slabs + (size_t)(slabRow + tx + 1) * SLAB
                     + BASE27[pobase + 0] + rowoff * 6;
            #pragma unroll
            for (int k = 0; k < 6; ++k) d[k] = src[21 + k];
        }
    }
}

// ---------------------------------------------------------------------------
// Kernel 3: gather, per-cell. One thread per output cell sums its 1..8
// covering slab pieces directly from global (each slab float read exactly
// once) and fuses the spill RMW on out. No LDS, no __syncthreads.
//
// Piece (jz,jy,jx) of dest tile d comes from source tile s = d + (j - 1):
//   j=1: own tile, covers local coord [0,16), piece-local p = c, ext 16
//   j=0: source d-1 (needs t>0),  covers c in [0,6),   p = c,      ext 6
//   j=2: source d+1 (needs t<7),  covers c in [11,16), p = c - 11, ext 5
// off = (pz*EXT[jy] + py)*EXT[jx] + px, base BASE27[jz*9+jy*3+jx].
// ---------------------------------------------------------------------------
__global__ __launch_bounds__(NTHR) void gather_tile_kernel(const float* __restrict__ slabs,
                                                           float* __restrict__ out) {
    const int blk = blockIdx.x;              // 0 .. 2*NTILE-1
    const int n = blk >> 9;
    const int t = blk & (NTILE - 1);
    const int tx = t & 7, ty = (t >> 3) & 7, tz = t >> 6;

    const float* __restrict__ slab = slabs + (size_t)blk * SLAB;
    float* __restrict__ ob = out + (size_t)n * NP;

    for (int i = threadIdx.x; i < TS * TS * TS; i += NTHR) {
        const int x = i & 15, y = (i >> 4) & 15, z = i >> 8;

        // second-piece candidates per axis: (sec term, piece coord, extent)
        int zt2 = 0, zp2 = 0, ze2 = 0; bool z2 = false;
        if (z < 6)        { if (tz > 0)       { zt2 = 0;  zp2 = z;      ze2 = 6; z2 = true; } }
        else if (z >= 11) { if (tz < TPB - 1) { zt2 = 18; zp2 = z - 11; ze2 = 5; z2 = true; } }
        int yt2 = 0, yp2 = 0, ye2 = 0; bool y2 = false;
        if (y < 6)        { if (ty > 0)       { yt2 = 0;  yp2 = y;      ye2 = 6; y2 = true; } }
        else if (y >= 11) { if (ty < TPB - 1) { yt2 = 6;  yp2 = y - 11; ye2 = 5; y2 = true; } }
        int xt2 = 0, xp2 = 0, xe2 = 0; bool x2 = false;
        if (x < 6)        { if (tx > 0)       { xt2 = 0;  xp2 = x;      xe2 = 6; x2 = true; } }
        else if (x >= 11) { if (tx < TPB - 1) { xt2 = 2;  xp2 = x - 11; xe2 = 5; x2 = true; } }

        // (jz=1, jy=1, jx=1) center piece: always present
        float s = slab[BASE27[13] + (z * 16 + y) * 16 + x];
        if (x2) s += slab[BASE27[9 + 3 + xt2] + (z * 16 + y) * xe2 + xp2];
        if (y2) {
            s += slab[BASE27[9 + yt2 + 1] + (z * ye2 + yp2) * 16 + x];
            if (x2) s += slab[BASE27[9 + yt2 + xt2] + (z * ye2 + yp2) * xe2 + xp2];
        }
        if (z2) {
            s += slab[BASE27[zt2 + 3 + 1] + (zp2 * 16 + y) * 16 + x];
            if (x2) s += slab[BASE27[zt2 + 3 + xt2] + (zp2 * 16 + y) * xe2 + xp2];
            if (y2) {
                s += slab[BASE27[zt2 + yt2 + 1] + (zp2 * ye2 + yp2) * 16 + x];
                if (x2) s += slab[BASE27[zt2 + yt2 + xt2] + (zp2 * ye2 + yp2) * xe2 + xp2];
            }
        }

        const size_t g = (((size_t)(tz * TS + z) * NDIM) + ty * TS + y) * NDIM
                       + tx * TS + x;
        ob[g] += s;      // out holds spill deposits from scatter
    }
}

// ---------------------------------------------------------------------------
// Fallback (small ws): direct device-scope atomic scatter into out
// ---------------------------------------------------------------------------
__global__ __launch_bounds__(256) void scatter_direct_kernel(const float* __restrict__ x,
                                                             const float* __restrict__ ws,
                                                             float* __restrict__ out) {
    const int lin = blockIdx.x * 256 + threadIdx.x;
    const int n = lin >> 21;
    const int p = lin & (NP - 1);

    float m0, m1, m2;
    load_means128(ws, n, m0, m1, m2);

    const size_t base = (size_t)n * 4 * NP;
    const float d0 = x[base + 0 * (size_t)NP + p];
    const float d1 = x[base + 1 * (size_t)NP + p];
    const float d2 = x[base + 2 * (size_t)NP + p];
    const float v  = x[base + 3 * (size_t)NP + p];

    const int w = p & 127, h = (p >> 7) & 127, d = p >> 14;
    const float pd = (d0 - m0) * DIS_NORM + (float)d + 0.5f;
    const float ph = (d1 - m1) * DIS_NORM + (float)h + 0.5f;
    const float pw = (d2 - m2) * DIS_NORM + (float)w + 0.5f;
    const float fd = floorf(pd), fh = floorf(ph), fw = floorf(pw);
    const int id = (int)fd, ih = (int)fh, iw = (int)fw;
    const float rd = pd - fd, rh = ph - fh, rw = pw - fw;
    const float wd[2] = {1.0f - rd, rd}, wh[2] = {1.0f - rh, rh}, ww[2] = {1.0f - rw, rw};
    float* o = out + (size_t)n * NP;
    #pragma unroll
    for (int dd = 0; dd < 2; ++dd) {
        const int td = id + dd;
        if ((unsigned)td >= (unsigned)NDIM) continue;
        #pragma unroll
        for (int hh = 0; hh < 2; ++hh) {
            const int th = ih + hh;
            if ((unsigned)th >= (unsigned)NDIM) continue;
            const float vdh = v * wd[dd] * wh[hh];
            const int rowbase = (td * NDIM + th) * NDIM;
            #pragma unroll
            for (int wi = 0; wi < 2; ++wi) {
                const int tw = iw + wi;
                if ((unsigned)tw >= (unsigned)NDIM) continue;
                atomicAdd(o + rowbase + tw, vdh * ww[wi]);
            }
        }
    }
}

extern "C" void kernel_launch(void* const* d_in, const int* in_sizes, int n_in,
                              void* d_out, int out_size, void* d_ws, size_t ws_size,
                              hipStream_t stream) {
    const float* x = (const float*)d_in[0];
    float* out = (float*)d_out;
    float* ws = (float*)d_ws;
    float* slabs = ws + SLABS_OFF;

    dim3 pgrid(128, 7);   // 6 sum planes + 1 out-zero plane

    if (ws_size >= WS_NEEDED_BYTES) {
        prep_kernel<<<pgrid, 256, 0, stream>>>(x, ws, out);
        scatter_tile_kernel<<<dim3(NBATCH * NTILE), NTHR, 0, stream>>>(x, ws, slabs, out);
        gather_tile_kernel<<<dim3(NBATCH * NTILE), NTHR, 0, stream>>>(slabs, out);
    } else {
        prep_kernel<<<pgrid, 256, 0, stream>>>(x, ws, out);
        scatter_direct_kernel<<<dim3(NBATCH * NP / 256), 256, 0, stream>>>(x, ws, out);
    }
}

// Round 4
// 236.765 us; speedup vs baseline: 1.3614x; 1.3614x over previous
//
#include <hip/hip_runtime.h>

// Problem constants (fixed by reference: x is (2, 4, 128, 128, 128) fp32)
#define NBATCH 2
#define NDIM   128
#define NP     (128 * 128 * 128)        // particles per batch = mesh cells (2^21)
#define DIS_NORM 3.072f                  // 6 * 512 / 1000

// Tiling: 16^3 origin tiles; LDS window halo LO=3 below, HI=4 above.
// WIN=23 -> 12167 cells as PACKED u64 pairs, 2^-24 fixed point (native int
// LDS atomics -- fp32 LDS atomicAdd compiles to a CAS loop, 2.7x slower,
// measured round 3). ~50.8 KB LDS -> 3 blocks/CU (24 waves) in scatter.
#define TS   16
#define LO   3
#define HI   4
#define WIN  (TS + LO + HI)              // 23
#define WIN2 (WIN * WIN)                 // 529
#define WINF (WIN * WIN * WIN)           // 12167
#define TPB  8
#define NTILE (TPB * TPB * TPB)          // 512 tiles per batch
#define NTHR 512

#define FXSCALE 16777216.0f              // 2^24
#define FXINV   (1.0f / 16777216.0f)

// Spill queue: expected ~390 slow particles/block (9.6% of 4096, sigma~19);
// 1024 is >> 30 sigma. Overflow falls back to inline slow_deposit.
#define QCAP 1024

// Destination-major inbox: each dest tile owns a contiguous slab of 27
// pieces (extents by j: {4,16,3}; j=0 from src d-1 covers c in [0,4),
// j=1 own covers [0,16), j=2 from src d+1 covers c in [13,16)),
// piece bases padded to 4 floats. Slab = 12167 -> 12168 floats.
#define SLAB 12168

// ws layout (floats): [0..1024) partial sums; [1024..) per-tile slabs
#define SUMS_OFF 0
#define SLABS_OFF 1024
#define WS_FLOATS ((size_t)SLABS_OFF + (size_t)NBATCH * NTILE * SLAB)
#define WS_NEEDED_BYTES (WS_FLOATS * sizeof(float))

// Cumulative piece bases for extents e={4,16,3}, each piece padded to x4.
__device__ __constant__ int BASE27[27] = {
    0,64,320,368,624,1648,1840,1888,2080,
    2116,2372,3396,3588,4612,8708,9476,9668,10436,
    10580,10628,10820,10856,11048,11816,11960,11996,12140};

// ---------------------------------------------------------------------------
// Kernel 1: prep. Planes 0..5: per-block partial sums of displacement
// channels. Plane 6: zero d_out (spill deposits land there as u32 fixed pt).
// ---------------------------------------------------------------------------
__global__ __launch_bounds__(256) void prep_kernel(const float* __restrict__ x,
                                                   float* __restrict__ ws,
                                                   float* __restrict__ out) {
    const int plane = blockIdx.y;
    if (plane < 6) {
        const int n = plane / 3, c = plane % 3;
        const float4* xp = (const float4*)(x + ((size_t)n * 4 + c) * NP);
        float s = 0.0f;
        for (int i = blockIdx.x * 256 + threadIdx.x; i < NP / 4; i += 128 * 256) {
            float4 v = xp[i];
            s += (v.x + v.y) + (v.z + v.w);
        }
        #pragma unroll
        for (int off = 32; off > 0; off >>= 1) s += __shfl_down(s, off, 64);
        __shared__ float wsum[4];
        if ((threadIdx.x & 63) == 0) wsum[threadIdx.x >> 6] = s;
        __syncthreads();
        if (threadIdx.x == 0)
            ws[SUMS_OFF + plane * 128 + blockIdx.x] =
                (wsum[0] + wsum[1]) + (wsum[2] + wsum[3]);
    } else {
        float4* o4 = (float4*)out;
        const float4 z = make_float4(0.f, 0.f, 0.f, 0.f);
        for (int i = blockIdx.x * 256 + threadIdx.x; i < NBATCH * NP / 4; i += 128 * 256)
            o4[i] = z;
    }
}

// Fallback-path means (serial 128-sum; only used by scatter_direct_kernel).
__device__ __forceinline__ void load_means128(const float* __restrict__ ws, int n,
                                              float& m0, float& m1, float& m2) {
    float s0 = 0.f, s1 = 0.f, s2 = 0.f;
    const float* p0 = ws + SUMS_OFF + (n * 3 + 0) * 128;
    const float* p1 = ws + SUMS_OFF + (n * 3 + 1) * 128;
    const float* p2 = ws + SUMS_OFF + (n * 3 + 2) * 128;
    #pragma unroll 4
    for (int b = 0; b < 128; ++b) { s0 += p0[b]; s1 += p1[b]; s2 += p2[b]; }
    const float inv_np = 1.0f / (float)NP;
    m0 = s0 * inv_np; m1 = s1 * inv_np; m2 = s2 * inv_np;
}

// Packed pair deposit: cells (b, b+1) get (va, vb) in 2^-24 fixed point.
__device__ __forceinline__ void deposit_pair(unsigned long long* __restrict__ winU,
                                             int b, float va, float vb) {
    const int fa = __float2int_rn(va * FXSCALE);
    const int fb = __float2int_rn(vb * FXSCALE);
    const bool odd = (b & 1);
    const long long packed = (((long long)fb) << 32) + (long long)fa;
    const long long hiOnly = ((long long)fa) << 32;
    atomicAdd(&winU[b >> 1], (unsigned long long)(odd ? hiOnly : packed));
    if (odd) atomicAdd(&winU[(b >> 1) + 1], (unsigned long long)(long long)fb);
}

// General-case deposit: window cells -> packed u64 LDS atomics; in-mesh but
// out-of-window -> native u32 fixed-point global atomics on out (decoded by
// gather). No fp atomics anywhere (CAS-loop hazard, measured round 3).
__device__ __forceinline__ void slow_deposit(unsigned long long* __restrict__ winU,
                                             unsigned int* __restrict__ spU,
                                             float pd, float ph, float pw, float v,
                                             int od, int oh, int ow) {
    const float fd = floorf(pd), fh = floorf(ph), fw = floorf(pw);
    const int id = (int)fd, ih = (int)fh, iw = (int)fw;
    const float rd = pd - fd, rh = ph - fh, rw = pw - fw;
    const int wd = id - od, wh = ih - oh, ww = iw - ow;
    const float wd2[2] = {1.0f - rd, rd};
    const float wh2[2] = {1.0f - rh, rh};
    const float ww2[2] = {1.0f - rw, rw};
    #pragma unroll
    for (int dd = 0; dd < 2; ++dd) {
        const int td = id + dd, wdc = wd + dd;
        const bool dW = (unsigned)wdc < WIN, dM = (unsigned)td < NDIM;
        if (!dM && !dW) continue;
        #pragma unroll
        for (int hh = 0; hh < 2; ++hh) {
            const int th = ih + hh, whc = wh + hh;
            const bool hW = (unsigned)whc < WIN, hM = (unsigned)th < NDIM;
            const float vdh = v * wd2[dd] * wh2[hh];
            #pragma unroll
            for (int wi = 0; wi < 2; ++wi) {
                const int tw = iw + wi, wwc = ww + wi;
                const bool wW = (unsigned)wwc < WIN, wM = (unsigned)tw < NDIM;
                const float dep = vdh * ww2[wi];
                const int fx = __float2int_rn(dep * FXSCALE);
                if (dW && hW && wW) {
                    const int cb = (wdc * WIN + whc) * WIN + wwc;
                    const long long cv = (cb & 1)
                        ? (((long long)fx) << 32) : (long long)fx;
                    atomicAdd(&winU[cb >> 1], (unsigned long long)cv);
                } else if (dM && hM && wM) {
                    atomicAdd(spU + ((size_t)td * NDIM + th) * NDIM + tw,
                              (unsigned int)fx);
                }
            }
        }
    }
}

// ---------------------------------------------------------------------------
// Kernel 2: tiled CIC scatter + destination-major flush. WIN=23 window in
// packed u64 fixed point; spill queue drains ~9.6% slow particles with all
// lanes active; 3 blocks/CU.
// ---------------------------------------------------------------------------
__global__ __launch_bounds__(NTHR, 6) void scatter_tile_kernel(
        const float* __restrict__ x, const float* __restrict__ ws,
        float* __restrict__ slabs, float* __restrict__ out) {
    const int blk = blockIdx.x;              // 0 .. 2*NTILE-1
    const int n = blk >> 9;
    const int t = blk & (NTILE - 1);
    const int tx = t & 7, ty = (t >> 3) & 7, tz = t >> 6;

    __shared__ ulonglong2 win2[(WINF + 3) / 4 + 1];   // 48688 B
    __shared__ float smean[3];
    __shared__ int qcount;
    __shared__ unsigned short queue[QCAP];            // 2048 B
    unsigned long long* winU = (unsigned long long*)win2;
    {
        float4* z4 = (float4*)win2;
        const float4 z = make_float4(0.f, 0.f, 0.f, 0.f);
        for (int i = threadIdx.x; i < (WINF + 3) / 4 + 1; i += NTHR) z4[i] = z;
        if (threadIdx.x == 0) qcount = 0;
    }
    // means: waves 0..2 each reduce one channel's 128 partials (deterministic)
    if (threadIdx.x < 192) {
        const int c = threadIdx.x >> 6;      // 0..2
        const int l = threadIdx.x & 63;
        const float* p = ws + SUMS_OFF + (n * 3 + c) * 128;
        float s = p[l] + p[l + 64];
        #pragma unroll
        for (int off = 32; off > 0; off >>= 1) s += __shfl_down(s, off, 64);
        if (l == 0) smean[c] = s * (1.0f / (float)NP);
    }
    __syncthreads();
    const float m0 = smean[0], m1 = smean[1], m2 = smean[2];

    // ---- deposit phase: 512 threads x 8 particles ----
    const int i0 = threadIdx.x * 8;
    const int lw0 = i0 & 15;
    const int lh  = (i0 >> 4) & 15;
    const int ld  = i0 >> 8;
    const int gd = tz * TS + ld, gh = ty * TS + lh, gw0 = tx * TS + lw0;
    const size_t prow = ((size_t)gd * NDIM + gh) * NDIM + gw0;

    const float4* x4 = (const float4*)(x + (size_t)n * 4 * NP);
    const size_t q = prow >> 2;
    const size_t s4 = NP / 4;
    float4 a0 = x4[0 * s4 + q], a1 = x4[0 * s4 + q + 1];
    float4 b0 = x4[1 * s4 + q], b1 = x4[1 * s4 + q + 1];
    float4 c0 = x4[2 * s4 + q], c1 = x4[2 * s4 + q + 1];
    float4 e0 = x4[3 * s4 + q], e1 = x4[3 * s4 + q + 1];
    const float D0[8] = {a0.x, a0.y, a0.z, a0.w, a1.x, a1.y, a1.z, a1.w};
    const float D1[8] = {b0.x, b0.y, b0.z, b0.w, b1.x, b1.y, b1.z, b1.w};
    const float D2[8] = {c0.x, c0.y, c0.z, c0.w, c1.x, c1.y, c1.z, c1.w};
    const float VV[8] = {e0.x, e0.y, e0.z, e0.w, e1.x, e1.y, e1.z, e1.w};

    const int od = tz * TS - LO, oh = ty * TS - LO, ow = tx * TS - LO;
    unsigned int* spU = (unsigned int*)(out + (size_t)n * NP);

    #pragma unroll
    for (int k = 0; k < 8; ++k) {
        const float pd = (D0[k] - m0) * DIS_NORM + (float)gd + 0.5f;
        const float ph = (D1[k] - m1) * DIS_NORM + (float)gh + 0.5f;
        const float pw = (D2[k] - m2) * DIS_NORM + (float)(gw0 + k) + 0.5f;
        const float v = VV[k];

        const float fd = floorf(pd), fh = floorf(ph), fw = floorf(pw);
        const int id = (int)fd, ih = (int)fh, iw = (int)fw;
        const float rd = pd - fd, rh = ph - fh, rw = pw - fw;

        const int wd = id - od, wh = ih - oh, ww = iw - ow;
        if ((unsigned)wd <= WIN - 2 && (unsigned)wh <= WIN - 2 &&
            (unsigned)ww <= WIN - 2) {
            const int b00 = (wd * WIN + wh) * WIN + ww;
            const float sd0 = v * (1.0f - rd), sd1 = v * rd;
            const float h0 = 1.0f - rh, h1 = rh;
            const float q0 = 1.0f - rw, q1 = rw;
            deposit_pair(winU, b00,              sd0 * h0 * q0, sd0 * h0 * q1);
            deposit_pair(winU, b00 + WIN,        sd0 * h1 * q0, sd0 * h1 * q1);
            deposit_pair(winU, b00 + WIN2,       sd1 * h0 * q0, sd1 * h0 * q1);
            deposit_pair(winU, b00 + WIN2 + WIN, sd1 * h1 * q0, sd1 * h1 * q1);
        } else {
            const int qi = atomicAdd(&qcount, 1);
            if (qi < QCAP) {
                queue[qi] = (unsigned short)(i0 + k);
            } else {
                slow_deposit(winU, spU, pd, ph, pw, v, od, oh, ow);
            }
        }
    }

    __syncthreads();

    // ---- drain spill queue: all lanes active, ~390 entries/block ----
    {
        const int nq = min(qcount, QCAP);
        const float* xb = x + (size_t)n * 4 * NP;
        for (int qi = threadIdx.x; qi < nq; qi += NTHR) {
            const int p = queue[qi];
            const int lw = p & 15, lhq = (p >> 4) & 15, ldq = p >> 8;
            const int gdq = tz * TS + ldq, ghq = ty * TS + lhq, gwq = tx * TS + lw;
            const size_t pr = ((size_t)gdq * NDIM + ghq) * NDIM + gwq;
            const float pd = (xb[pr] - m0) * DIS_NORM + (float)gdq + 0.5f;
            const float ph = (xb[(size_t)NP + pr] - m1) * DIS_NORM + (float)ghq + 0.5f;
            const float pw = (xb[2 * (size_t)NP + pr] - m2) * DIS_NORM + (float)gwq + 0.5f;
            const float v = xb[3 * (size_t)NP + pr];
            slow_deposit(winU, spU, pd, ph, pw, v, od, oh, ow);
        }
    }
    __syncthreads();

    // ---- decode pass: in-place u64 fixed-point -> 2x fp32 (no races) ----
    {
        const int NU = (WINF + 1) / 2;   // 6084
        for (int i = threadIdx.x; i < NU; i += NTHR) {
            const unsigned long long u = winU[i];
            const int lo = (int)(unsigned)(u & 0xffffffffull);
            const int hi = (int)(u >> 32) + (lo < 0 ? 1 : 0);
            float2 f;
            f.x = (float)lo * FXINV;
            f.y = (float)hi * FXINV;
            ((float2*)winU)[i] = f;
        }
    }
    __syncthreads();
    const float* winF = (const float*)winU;

    // ---- flush: one thread per (lz,ly) row; 3 fixed x-segments ----
    // window coord w: w<3 -> dest t-1 piece j=2 (p=w, ext 3);
    // 3<=w<19 -> own j=1 (p=w-3, ext 16); w>=19 -> dest t+1 j=0 (p=w-19, ext 4)
    const int EXTY[3] = {4, 16, 3};
    const int nbase = n << 9;
    for (int r = threadIdx.x; r < WIN2; r += NTHR) {
        const int lz = r / WIN;
        const int ly = r - lz * WIN;
        int mz, pz;
        if (lz < LO) { mz = -1; pz = lz; }
        else if (lz < LO + TS) { mz = 0; pz = lz - LO; }
        else { mz = 1; pz = lz - LO - TS; }
        int my, py;
        if (ly < LO) { my = -1; py = ly; }
        else if (ly < LO + TS) { my = 0; py = ly - LO; }
        else { my = 1; py = ly - LO - TS; }
        const int dtz = tz + mz, dty = ty + my;
        if ((unsigned)dtz >= TPB || (unsigned)dty >= TPB) continue;

        const int jz = 1 - mz, jy = 1 - my;
        const int ey = EXTY[jy];
        const int rowoff = pz * ey + py;
        const int pobase = jz * 9 + jy * 3;
        const float* src = winF + r * WIN;
        const int slabRow = nbase + (dtz * 8 + dty) * 8;

        // seg A: jx=2 (dest tile tx-1), lx 0..2, ex=3
        if (tx > 0) {
            float* d = slabs + (size_t)(slabRow + tx - 1) * SLAB
                     + BASE27[pobase + 2] + rowoff * 3;
            #pragma unroll
            for (int k = 0; k < 3; ++k) d[k] = src[k];
        }
        // seg B: jx=1 (own tile), lx 3..18, ex=16, aligned float4 stores
        {
            float* d = slabs + (size_t)(slabRow + tx) * SLAB
                     + BASE27[pobase + 1] + rowoff * 16;
            #pragma unroll
            for (int k = 0; k < 4; ++k) {
                float4 v;
                v.x = src[3 + 4 * k]; v.y = src[4 + 4 * k];
                v.z = src[5 + 4 * k]; v.w = src[6 + 4 * k];
                ((float4*)d)[k] = v;
            }
        }
        // seg C: jx=0 (dest tile tx+1), lx 19..22, ex=4, one float4 store
        if (tx < TPB - 1) {
            float* d = slabs + (size_t)(slabRow + tx + 1) * SLAB
                     + BASE27[pobase + 0] + rowoff * 4;
            float4 v;
            v.x = src[19]; v.y = src[20]; v.z = src[21]; v.w = src[22];
            *(float4*)d = v;
        }
    }
}

// ---------------------------------------------------------------------------
// Kernel 3: gather, per-cell. One thread per output cell sums its 1..8
// covering slab pieces directly from global (each slab float read exactly
// once), decodes the u32 fixed-point spill word in out, writes float.
//
// Dest-local coverage: j=0 piece (src d-1) covers c in [0,4), p=c, ext 4;
// j=1 own covers [0,16), p=c, ext 16; j=2 (src d+1) covers [13,16),
// p=c-13, ext 3. off = (pz*EXT[jy]+py)*EXT[jx]+px, base BASE27[jz*9+jy*3+jx].
// ---------------------------------------------------------------------------
__global__ __launch_bounds__(NTHR) void gather_tile_kernel(const float* __restrict__ slabs,
                                                           float* __restrict__ out) {
    const int blk = blockIdx.x;              // 0 .. 2*NTILE-1
    const int n = blk >> 9;
    const int t = blk & (NTILE - 1);
    const int tx = t & 7, ty = (t >> 3) & 7, tz = t >> 6;

    const float* __restrict__ slab = slabs + (size_t)blk * SLAB;
    float* __restrict__ ob = out + (size_t)n * NP;
    const unsigned int* __restrict__ obU = (const unsigned int*)ob;

    for (int i = threadIdx.x; i < TS * TS * TS; i += NTHR) {
        const int x = i & 15, y = (i >> 4) & 15, z = i >> 8;

        // second-piece candidates per axis: (sec term, piece coord, extent)
        int zt2 = 0, zp2 = 0, ze2 = 0; bool z2 = false;
        if (z < 4)        { if (tz > 0)       { zt2 = 0;  zp2 = z;      ze2 = 4; z2 = true; } }
        else if (z >= 13) { if (tz < TPB - 1) { zt2 = 18; zp2 = z - 13; ze2 = 3; z2 = true; } }
        int yt2 = 0, yp2 = 0, ye2 = 0; bool y2 = false;
        if (y < 4)        { if (ty > 0)       { yt2 = 0;  yp2 = y;      ye2 = 4; y2 = true; } }
        else if (y >= 13) { if (ty < TPB - 1) { yt2 = 6;  yp2 = y - 13; ye2 = 3; y2 = true; } }
        int xt2 = 0, xp2 = 0, xe2 = 0; bool x2 = false;
        if (x < 4)        { if (tx > 0)       { xt2 = 0;  xp2 = x;      xe2 = 4; x2 = true; } }
        else if (x >= 13) { if (tx < TPB - 1) { xt2 = 2;  xp2 = x - 13; xe2 = 3; x2 = true; } }

        // (jz=1, jy=1, jx=1) center piece: always present
        float s = slab[BASE27[13] + (z * 16 + y) * 16 + x];
        if (x2) s += slab[BASE27[9 + 3 + xt2] + (z * 16 + y) * xe2 + xp2];
        if (y2) {
            s += slab[BASE27[9 + yt2 + 1] + (z * ye2 + yp2) * 16 + x];
            if (x2) s += slab[BASE27[9 + yt2 + xt2] + (z * ye2 + yp2) * xe2 + xp2];
        }
        if (z2) {
            s += slab[BASE27[zt2 + 3 + 1] + (zp2 * 16 + y) * 16 + x];
            if (x2) s += slab[BASE27[zt2 + 3 + xt2] + (zp2 * 16 + y) * xe2 + xp2];
            if (y2) {
                s += slab[BASE27[zt2 + yt2 + 1] + (zp2 * ye2 + yp2) * 16 + x];
                if (x2) s += slab[BASE27[zt2 + yt2 + xt2] + (zp2 * ye2 + yp2) * xe2 + xp2];
            }
        }

        const size_t g = (((size_t)(tz * TS + z) * NDIM) + ty * TS + y) * NDIM
                       + tx * TS + x;
        // out holds u32 fixed-point spill deposits: decode and add
        s += (float)(int)obU[g] * FXINV;
        ob[g] = s;
    }
}

// ---------------------------------------------------------------------------
// Fallback (small ws): direct device-scope atomic scatter into out
// ---------------------------------------------------------------------------
__global__ __launch_bounds__(256) void scatter_direct_kernel(const float* __restrict__ x,
                                                             const float* __restrict__ ws,
                                                             float* __restrict__ out) {
    const int lin = blockIdx.x * 256 + threadIdx.x;
    const int n = lin >> 21;
    const int p = lin & (NP - 1);

    float m0, m1, m2;
    load_means128(ws, n, m0, m1, m2);

    const size_t base = (size_t)n * 4 * NP;
    const float d0 = x[base + 0 * (size_t)NP + p];
    const float d1 = x[base + 1 * (size_t)NP + p];
    const float d2 = x[base + 2 * (size_t)NP + p];
    const float v  = x[base + 3 * (size_t)NP + p];

    const int w = p & 127, h = (p >> 7) & 127, d = p >> 14;
    const float pd = (d0 - m0) * DIS_NORM + (float)d + 0.5f;
    const float ph = (d1 - m1) * DIS_NORM + (float)h + 0.5f;
    const float pw = (d2 - m2) * DIS_NORM + (float)w + 0.5f;
    const float fd = floorf(pd), fh = floorf(ph), fw = floorf(pw);
    const int id = (int)fd, ih = (int)fh, iw = (int)fw;
    const float rd = pd - fd, rh = ph - fh, rw = pw - fw;
    const float wd[2] = {1.0f - rd, rd}, wh[2] = {1.0f - rh, rh}, ww[2] = {1.0f - rw, rw};
    float* o = out + (size_t)n * NP;
    #pragma unroll
    for (int dd = 0; dd < 2; ++dd) {
        const int td = id + dd;
        if ((unsigned)td >= (unsigned)NDIM) continue;
        #pragma unroll
        for (int hh = 0; hh < 2; ++hh) {
            const int th = ih + hh;
            if ((unsigned)th >= (unsigned)NDIM) continue;
            const float vdh = v * wd[dd] * wh[hh];
            const int rowbase = (td * NDIM + th) * NDIM;
            #pragma unroll
            for (int wi = 0; wi < 2; ++wi) {
                const int tw = iw + wi;
                if ((unsigned)tw >= (unsigned)NDIM) continue;
                atomicAdd(o + rowbase + tw, vdh * ww[wi]);
            }
        }
    }
}

extern "C" void kernel_launch(void* const* d_in, const int* in_sizes, int n_in,
                              void* d_out, int out_size, void* d_ws, size_t ws_size,
                              hipStream_t stream) {
    const float* x = (const float*)d_in[0];
    float* out = (float*)d_out;
    float* ws = (float*)d_ws;
    float* slabs = ws + SLABS_OFF;

    dim3 pgrid(128, 7);   // 6 sum planes + 1 out-zero plane

    if (ws_size >= WS_NEEDED_BYTES) {
        prep_kernel<<<pgrid, 256, 0, stream>>>(x, ws, out);
        scatter_tile_kernel<<<dim3(NBATCH * NTILE), NTHR, 0, stream>>>(x, ws, slabs, out);
        gather_tile_kernel<<<dim3(NBATCH * NTILE), NTHR, 0, stream>>>(slabs, out);
    } else {
        prep_kernel<<<pgrid, 256, 0, stream>>>(x, ws, out);
        scatter_direct_kernel<<<dim3(NBATCH * NP / 256), 256, 0, stream>>>(x, ws, out);
    }
}

// Round 5
// 186.603 us; speedup vs baseline: 1.7274x; 1.2688x over previous
//
#include <hip/hip_runtime.h>

// Problem constants (fixed by reference: x is (2, 4, 128, 128, 128) fp32)
#define NBATCH 2
#define NDIM   128
#define NP     (128 * 128 * 128)        // particles per batch = mesh cells (2^21)
#define DIS_NORM 3.072f                  // 6 * 512 / 1000

// Tiling: 16^3 origin tiles; LDS window halo LO=5 below, HI=6 above.
// WIN=27 -> 19683 cells as PACKED u64 pairs (2 cells/word), 2^-24 fixed point,
// native u64 LDS atomics (fp32 LDS atomicAdd is a CAS loop: 2.7x slower,
// measured r3; WIN=23 spill blowup: +47us, measured r4). ~81.3 KB LDS ->
// 2 blocks/CU. This is the measured optimum operating point (70 us).
#define TS   16
#define LO   5
#define HI   6
#define WIN  (TS + LO + HI)              // 27
#define WIN2 (WIN * WIN)                 // 729
#define WINF (WIN * WIN * WIN)           // 19683
#define TPB  8
#define NTILE (TPB * TPB * TPB)          // 512 tiles per batch
#define NTHR 512

#define FXSCALE 16777216.0f              // 2^24
#define FXINV   (1.0f / 16777216.0f)

// Spill queue: expected ~98 slow particles/block (2.4% of 4096); 1280 >> 13 sigma.
#define QCAP 1280

// Destination-major inbox: each dest tile owns a contiguous slab of 27
// pieces (source offset o = src - dest; extents by j = 1 - m: {6,16,5}),
// piece bases padded to 4 floats. Slab = 19692 -> 19696 floats.
#define SLAB 19696

// ws layout (floats): [0..1024) partial sums; [1024..) per-tile slabs
#define SUMS_OFF 0
#define SLABS_OFF 1024
#define WS_FLOATS ((size_t)SLABS_OFF + (size_t)NBATCH * NTILE * SLAB)
#define WS_NEEDED_BYTES (WS_FLOATS * sizeof(float))

// Cumulative piece bases for extents e={6,16,5}, each piece padded to x4.
// All entries divisible by 4 (float4-addressable).
__device__ __constant__ int BASE27[27] = {
    0,216,792,972,1548,3084,3564,3744,4224,
    4376,4952,6488,6968,8504,12600,13880,14360,15640,
    16040,16220,16700,16852,17332,18612,19012,19164,19564};

// ---------------------------------------------------------------------------
// Kernel 1: prep. Planes 0..5: per-block partial sums of displacement
// channels. Plane 6: zero d_out (float spill deposits land there atomically).
// ---------------------------------------------------------------------------
__global__ __launch_bounds__(256) void prep_kernel(const float* __restrict__ x,
                                                   float* __restrict__ ws,
                                                   float* __restrict__ out) {
    const int plane = blockIdx.y;
    if (plane < 6) {
        const int n = plane / 3, c = plane % 3;
        const float4* xp = (const float4*)(x + ((size_t)n * 4 + c) * NP);
        float s = 0.0f;
        for (int i = blockIdx.x * 256 + threadIdx.x; i < NP / 4; i += 128 * 256) {
            float4 v = xp[i];
            s += (v.x + v.y) + (v.z + v.w);
        }
        #pragma unroll
        for (int off = 32; off > 0; off >>= 1) s += __shfl_down(s, off, 64);
        __shared__ float wsum[4];
        if ((threadIdx.x & 63) == 0) wsum[threadIdx.x >> 6] = s;
        __syncthreads();
        if (threadIdx.x == 0)
            ws[SUMS_OFF + plane * 128 + blockIdx.x] =
                (wsum[0] + wsum[1]) + (wsum[2] + wsum[3]);
    } else {
        float4* o4 = (float4*)out;
        const float4 z = make_float4(0.f, 0.f, 0.f, 0.f);
        for (int i = blockIdx.x * 256 + threadIdx.x; i < NBATCH * NP / 4; i += 128 * 256)
            o4[i] = z;
    }
}

// Fallback-path means (serial 128-sum; only used by scatter_direct_kernel).
__device__ __forceinline__ void load_means128(const float* __restrict__ ws, int n,
                                              float& m0, float& m1, float& m2) {
    float s0 = 0.f, s1 = 0.f, s2 = 0.f;
    const float* p0 = ws + SUMS_OFF + (n * 3 + 0) * 128;
    const float* p1 = ws + SUMS_OFF + (n * 3 + 1) * 128;
    const float* p2 = ws + SUMS_OFF + (n * 3 + 2) * 128;
    #pragma unroll 4
    for (int b = 0; b < 128; ++b) { s0 += p0[b]; s1 += p1[b]; s2 += p2[b]; }
    const float inv_np = 1.0f / (float)NP;
    m0 = s0 * inv_np; m1 = s1 * inv_np; m2 = s2 * inv_np;
}

// Packed pair deposit: cells (b, b+1) get (va, vb) in 2^-24 fixed point.
__device__ __forceinline__ void deposit_pair(unsigned long long* __restrict__ winU,
                                             int b, float va, float vb) {
    const int fa = __float2int_rn(va * FXSCALE);
    const int fb = __float2int_rn(vb * FXSCALE);
    const bool odd = (b & 1);
    const long long packed = (((long long)fb) << 32) + (long long)fa;
    const long long hiOnly = ((long long)fa) << 32;
    atomicAdd(&winU[b >> 1], (unsigned long long)(odd ? hiOnly : packed));
    if (odd) atomicAdd(&winU[(b >> 1) + 1], (unsigned long long)(long long)fb);
}

// General-case deposit: window cells -> packed u64 LDS atomics; in-mesh but
// out-of-window -> float global atomics on out (rare: ~2.4% of particles have
// ANY out-of-window corner, and only those corners go global).
__device__ __forceinline__ void slow_deposit(unsigned long long* __restrict__ winU,
                                             float* __restrict__ sp,
                                             float pd, float ph, float pw, float v,
                                             int od, int oh, int ow) {
    const float fd = floorf(pd), fh = floorf(ph), fw = floorf(pw);
    const int id = (int)fd, ih = (int)fh, iw = (int)fw;
    const float rd = pd - fd, rh = ph - fh, rw = pw - fw;
    const int wd = id - od, wh = ih - oh, ww = iw - ow;
    const float wd2[2] = {1.0f - rd, rd};
    const float wh2[2] = {1.0f - rh, rh};
    const float ww2[2] = {1.0f - rw, rw};
    #pragma unroll
    for (int dd = 0; dd < 2; ++dd) {
        const int td = id + dd, wdc = wd + dd;
        const bool dW = (unsigned)wdc < WIN, dM = (unsigned)td < NDIM;
        if (!dM && !dW) continue;
        #pragma unroll
        for (int hh = 0; hh < 2; ++hh) {
            const int th = ih + hh, whc = wh + hh;
            const bool hW = (unsigned)whc < WIN, hM = (unsigned)th < NDIM;
            const float vdh = v * wd2[dd] * wh2[hh];
            #pragma unroll
            for (int wi = 0; wi < 2; ++wi) {
                const int tw = iw + wi, wwc = ww + wi;
                const bool wW = (unsigned)wwc < WIN, wM = (unsigned)tw < NDIM;
                const float dep = vdh * ww2[wi];
                if (dW && hW && wW) {
                    const int cb = (wdc * WIN + whc) * WIN + wwc;
                    const int fx = __float2int_rn(dep * FXSCALE);
                    const long long cv = (cb & 1)
                        ? (((long long)fx) << 32) : (long long)fx;
                    atomicAdd(&winU[cb >> 1], (unsigned long long)cv);
                } else if (dM && hM && wM) {
                    atomicAdd(sp + ((size_t)td * NDIM + th) * NDIM + tw, dep);
                }
            }
        }
    }
}

// ---------------------------------------------------------------------------
// Kernel 2: tiled CIC scatter + destination-major flush (r2-proven structure:
// WIN=27, u64 window, spill queue) + shuffle-based mean reduction.
// ---------------------------------------------------------------------------
__global__ __launch_bounds__(NTHR, 4) void scatter_tile_kernel(
        const float* __restrict__ x, const float* __restrict__ ws,
        float* __restrict__ slabs, float* __restrict__ out) {
    const int blk = blockIdx.x;              // 0 .. 2*NTILE-1
    const int n = blk >> 9;
    const int t = blk & (NTILE - 1);
    const int tx = t & 7, ty = (t >> 3) & 7, tz = t >> 6;

    __shared__ ulonglong2 win2[(WINF + 3) / 4 + 1];   // 78752 B
    __shared__ float smean[3];
    __shared__ int qcount;
    __shared__ unsigned short queue[QCAP];            // 2560 B
    unsigned long long* winU = (unsigned long long*)win2;
    {
        float4* z4 = (float4*)win2;
        const float4 z = make_float4(0.f, 0.f, 0.f, 0.f);
        for (int i = threadIdx.x; i < (WINF + 3) / 4 + 1; i += NTHR) z4[i] = z;
        if (threadIdx.x == 0) qcount = 0;
    }
    // means: waves 0..2 each reduce one channel's 128 partials (deterministic)
    if (threadIdx.x < 192) {
        const int c = threadIdx.x >> 6;      // 0..2
        const int l = threadIdx.x & 63;
        const float* p = ws + SUMS_OFF + (n * 3 + c) * 128;
        float s = p[l] + p[l + 64];
        #pragma unroll
        for (int off = 32; off > 0; off >>= 1) s += __shfl_down(s, off, 64);
        if (l == 0) smean[c] = s * (1.0f / (float)NP);
    }
    __syncthreads();
    const float m0 = smean[0], m1 = smean[1], m2 = smean[2];

    // ---- deposit phase: 512 threads x 8 particles ----
    const int i0 = threadIdx.x * 8;
    const int lw0 = i0 & 15;
    const int lh  = (i0 >> 4) & 15;
    const int ld  = i0 >> 8;
    const int gd = tz * TS + ld, gh = ty * TS + lh, gw0 = tx * TS + lw0;
    const size_t prow = ((size_t)gd * NDIM + gh) * NDIM + gw0;

    const float4* x4 = (const float4*)(x + (size_t)n * 4 * NP);
    const size_t q = prow >> 2;
    const size_t s4 = NP / 4;
    float4 a0 = x4[0 * s4 + q], a1 = x4[0 * s4 + q + 1];
    float4 b0 = x4[1 * s4 + q], b1 = x4[1 * s4 + q + 1];
    float4 c0 = x4[2 * s4 + q], c1 = x4[2 * s4 + q + 1];
    float4 e0 = x4[3 * s4 + q], e1 = x4[3 * s4 + q + 1];
    const float D0[8] = {a0.x, a0.y, a0.z, a0.w, a1.x, a1.y, a1.z, a1.w};
    const float D1[8] = {b0.x, b0.y, b0.z, b0.w, b1.x, b1.y, b1.z, b1.w};
    const float D2[8] = {c0.x, c0.y, c0.z, c0.w, c1.x, c1.y, c1.z, c1.w};
    const float VV[8] = {e0.x, e0.y, e0.z, e0.w, e1.x, e1.y, e1.z, e1.w};

    const int od = tz * TS - LO, oh = ty * TS - LO, ow = tx * TS - LO;
    float* sp = out + (size_t)n * NP;

    #pragma unroll
    for (int k = 0; k < 8; ++k) {
        const float pd = (D0[k] - m0) * DIS_NORM + (float)gd + 0.5f;
        const float ph = (D1[k] - m1) * DIS_NORM + (float)gh + 0.5f;
        const float pw = (D2[k] - m2) * DIS_NORM + (float)(gw0 + k) + 0.5f;
        const float v = VV[k];

        const float fd = floorf(pd), fh = floorf(ph), fw = floorf(pw);
        const int id = (int)fd, ih = (int)fh, iw = (int)fw;
        const float rd = pd - fd, rh = ph - fh, rw = pw - fw;

        const int wd = id - od, wh = ih - oh, ww = iw - ow;
        if ((unsigned)wd <= WIN - 2 && (unsigned)wh <= WIN - 2 &&
            (unsigned)ww <= WIN - 2) {
            const int b00 = (wd * WIN + wh) * WIN + ww;
            const float sd0 = v * (1.0f - rd), sd1 = v * rd;
            const float h0 = 1.0f - rh, h1 = rh;
            const float q0 = 1.0f - rw, q1 = rw;
            deposit_pair(winU, b00,              sd0 * h0 * q0, sd0 * h0 * q1);
            deposit_pair(winU, b00 + WIN,        sd0 * h1 * q0, sd0 * h1 * q1);
            deposit_pair(winU, b00 + WIN2,       sd1 * h0 * q0, sd1 * h0 * q1);
            deposit_pair(winU, b00 + WIN2 + WIN, sd1 * h1 * q0, sd1 * h1 * q1);
        } else {
            const int qi = atomicAdd(&qcount, 1);
            if (qi < QCAP) {
                queue[qi] = (unsigned short)(i0 + k);
            } else {
                slow_deposit(winU, sp, pd, ph, pw, v, od, oh, ow);
            }
        }
    }

    __syncthreads();

    // ---- drain spill queue: all lanes active, ~98 entries/block ----
    {
        const int nq = min(qcount, QCAP);
        const float* xb = x + (size_t)n * 4 * NP;
        for (int qi = threadIdx.x; qi < nq; qi += NTHR) {
            const int p = queue[qi];
            const int lw = p & 15, lhq = (p >> 4) & 15, ldq = p >> 8;
            const int gdq = tz * TS + ldq, ghq = ty * TS + lhq, gwq = tx * TS + lw;
            const size_t pr = ((size_t)gdq * NDIM + ghq) * NDIM + gwq;
            const float pd = (xb[pr] - m0) * DIS_NORM + (float)gdq + 0.5f;
            const float ph = (xb[(size_t)NP + pr] - m1) * DIS_NORM + (float)ghq + 0.5f;
            const float pw = (xb[2 * (size_t)NP + pr] - m2) * DIS_NORM + (float)gwq + 0.5f;
            const float v = xb[3 * (size_t)NP + pr];
            slow_deposit(winU, sp, pd, ph, pw, v, od, oh, ow);
        }
    }
    __syncthreads();

    // ---- decode pass: in-place u64 fixed-point -> 2x fp32 (no races) ----
    {
        const int NU = (WINF + 1) / 2;   // 9842
        for (int i = threadIdx.x; i < NU; i += NTHR) {
            const unsigned long long u = winU[i];
            const int lo = (int)(unsigned)(u & 0xffffffffull);
            const int hi = (int)(u >> 32) + (lo < 0 ? 1 : 0);
            float2 f;
            f.x = (float)lo * FXINV;
            f.y = (float)hi * FXINV;
            ((float2*)winU)[i] = f;
        }
    }
    __syncthreads();
    const float* winF = (const float*)winU;

    // ---- flush: one thread per (lz,ly) row; 3 fixed x-segments ----
    const int EXTY[3] = {6, 16, 5};
    const int nbase = n << 9;
    for (int r = threadIdx.x; r < WIN2; r += NTHR) {
        const int lz = r / WIN;
        const int ly = r - lz * WIN;
        int mz, pz;
        if (lz < LO) { mz = -1; pz = lz; }
        else if (lz < LO + TS) { mz = 0; pz = lz - LO; }
        else { mz = 1; pz = lz - LO - TS; }
        int my, py;
        if (ly < LO) { my = -1; py = ly; }
        else if (ly < LO + TS) { my = 0; py = ly - LO; }
        else { my = 1; py = ly - LO - TS; }
        const int dtz = tz + mz, dty = ty + my;
        if ((unsigned)dtz >= TPB || (unsigned)dty >= TPB) continue;

        const int jz = 1 - mz, jy = 1 - my;
        const int ey = EXTY[jy];
        const int rowoff = pz * ey + py;
        const int pobase = jz * 9 + jy * 3;
        const float* src = winF + r * WIN;
        const int slabRow = nbase + (dtz * 8 + dty) * 8;

        // seg A: jx=2 (dest tile tx-1), lx 0..4, ex=5
        if (tx > 0) {
            float* d = slabs + (size_t)(slabRow + tx - 1) * SLAB
                     + BASE27[pobase + 2] + rowoff * 5;
            #pragma unroll
            for (int k = 0; k < 5; ++k) d[k] = src[k];
        }
        // seg B: jx=1 (own tile), lx 5..20, ex=16, aligned float4 stores
        {
            float* d = slabs + (size_t)(slabRow + tx) * SLAB
                     + BASE27[pobase + 1] + rowoff * 16;
            #pragma unroll
            for (int k = 0; k < 4; ++k) {
                float4 v;
                v.x = src[5 + 4 * k]; v.y = src[6 + 4 * k];
                v.z = src[7 + 4 * k]; v.w = src[8 + 4 * k];
                ((float4*)d)[k] = v;
            }
        }
        // seg C: jx=0 (dest tile tx+1), lx 21..26, ex=6
        if (tx < TPB - 1) {
            float* d = slabs + (size_t)(slabRow + tx + 1) * SLAB
                     + BASE27[pobase + 0] + rowoff * 6;
            #pragma unroll
            for (int k = 0; k < 6; ++k) d[k] = src[21 + k];
        }
    }
}

// ---------------------------------------------------------------------------
// Kernel 3: gather, float4 per-quad. One thread handles 4 x-consecutive
// output cells. Center and all ext-16 (jx=1) pieces are aligned float4 loads
// (all BASE27 bases are x4-padded); only x-halo elements add scalars.
// Each slab float is read exactly once; out RMW is one float4.
//
// Dest-local coverage: j=0 piece (src d-1) covers c in [0,6), p=c, ext 6;
// j=1 own covers [0,16), ext 16; j=2 (src d+1) covers [11,16), p=c-11, ext 5.
// ---------------------------------------------------------------------------
__global__ __launch_bounds__(NTHR) void gather_tile_kernel(const float* __restrict__ slabs,
                                                           float* __restrict__ out) {
    const int blk = blockIdx.x;              // 0 .. 2*NTILE-1
    const int n = blk >> 9;
    const int t = blk & (NTILE - 1);
    const int tx = t & 7, ty = (t >> 3) & 7, tz = t >> 6;

    const float* __restrict__ slab = slabs + (size_t)blk * SLAB;
    const float4* __restrict__ slab4 = (const float4*)slab;
    float4* __restrict__ o4 = (float4*)(out + (size_t)n * NP);

    for (int i4 = threadIdx.x; i4 < TS * TS * TS / 4; i4 += NTHR) {
        const int xq = i4 & 3, y = (i4 >> 2) & 15, z = i4 >> 6;

        // y/z second-piece candidates: (sec offset, piece coord, extent)
        int ysec = 0, yp = 0, ye = 0; bool y2 = false;
        if (y < 6)        { if (ty > 0)       { ysec = 0; yp = y;      ye = 6; y2 = true; } }
        else if (y >= 11) { if (ty < TPB - 1) { ysec = 6; yp = y - 11; ye = 5; y2 = true; } }
        int zsec = 0, zp = 0, ze = 0; bool z2 = false;
        if (z < 6)        { if (tz > 0)       { zsec = 0;  zp = z;      ze = 6; z2 = true; } }
        else if (z >= 11) { if (tz < TPB - 1) { zsec = 18; zp = z - 11; ze = 5; z2 = true; } }

        const int rC = z * 16 + y;                       // center row index
        float4 s = slab4[(BASE27[13] >> 2) + rC * 4 + xq];
        int rY = 0, rZ = 0, rYZ = 0;
        if (y2) {
            rY = z * ye + yp;
            const float4 v = slab4[(BASE27[10 + ysec] >> 2) + rY * 4 + xq];
            s.x += v.x; s.y += v.y; s.z += v.z; s.w += v.w;
        }
        if (z2) {
            rZ = zp * 16 + y;
            const float4 v = slab4[(BASE27[zsec + 4] >> 2) + rZ * 4 + xq];
            s.x += v.x; s.y += v.y; s.z += v.z; s.w += v.w;
            if (y2) {
                rYZ = zp * ye + yp;
                const float4 v2 = slab4[(BASE27[zsec + ysec + 1] >> 2) + rYZ * 4 + xq];
                s.x += v2.x; s.y += v2.y; s.z += v2.z; s.w += v2.w;
            }
        }

        // x-halo scalar adds per element (x<6 or x>=11)
        float se[4] = {s.x, s.y, s.z, s.w};
        #pragma unroll
        for (int e = 0; e < 4; ++e) {
            const int x = xq * 4 + e;
            int xsec = 0, xp = 0, xe = 0; bool x2 = false;
            if (x < 6)        { if (tx > 0)       { xsec = 0; xp = x;      xe = 6; x2 = true; } }
            else if (x >= 11) { if (tx < TPB - 1) { xsec = 2; xp = x - 11; xe = 5; x2 = true; } }
            if (x2) {
                se[e] += slab[BASE27[12 + xsec] + rC * xe + xp];
                if (y2) se[e] += slab[BASE27[9 + ysec + xsec] + rY * xe + xp];
                if (z2) {
                    se[e] += slab[BASE27[zsec + 3 + xsec] + rZ * xe + xp];
                    if (y2) se[e] += slab[BASE27[zsec + ysec + xsec] + rYZ * xe + xp];
                }
            }
        }

        // out RMW (out holds float spill deposits from scatter)
        const size_t grow = ((size_t)(tz * TS + z) * NDIM + ty * TS + y) * (NDIM / 4)
                          + tx * 4 + xq;
        float4 o = o4[grow];
        o.x += se[0]; o.y += se[1]; o.z += se[2]; o.w += se[3];
        o4[grow] = o;
    }
}

// ---------------------------------------------------------------------------
// Fallback (small ws): direct device-scope atomic scatter into out
// ---------------------------------------------------------------------------
__global__ __launch_bounds__(256) void scatter_direct_kernel(const float* __restrict__ x,
                                                             const float* __restrict__ ws,
                                                             float* __restrict__ out) {
    const int lin = blockIdx.x * 256 + threadIdx.x;
    const int n = lin >> 21;
    const int p = lin & (NP - 1);

    float m0, m1, m2;
    load_means128(ws, n, m0, m1, m2);

    const size_t base = (size_t)n * 4 * NP;
    const float d0 = x[base + 0 * (size_t)NP + p];
    const float d1 = x[base + 1 * (size_t)NP + p];
    const float d2 = x[base + 2 * (size_t)NP + p];
    const float v  = x[base + 3 * (size_t)NP + p];

    const int w = p & 127, h = (p >> 7) & 127, d = p >> 14;
    const float pd = (d0 - m0) * DIS_NORM + (float)d + 0.5f;
    const float ph = (d1 - m1) * DIS_NORM + (float)h + 0.5f;
    const float pw = (d2 - m2) * DIS_NORM + (float)w + 0.5f;
    const float fd = floorf(pd), fh = floorf(ph), fw = floorf(pw);
    const int id = (int)fd, ih = (int)fh, iw = (int)fw;
    const float rd = pd - fd, rh = ph - fh, rw = pw - fw;
    const float wd[2] = {1.0f - rd, rd}, wh[2] = {1.0f - rh, rh}, ww[2] = {1.0f - rw, rw};
    float* o = out + (size_t)n * NP;
    #pragma unroll
    for (int dd = 0; dd < 2; ++dd) {
        const int td = id + dd;
        if ((unsigned)td >= (unsigned)NDIM) continue;
        #pragma unroll
        for (int hh = 0; hh < 2; ++hh) {
            const int th = ih + hh;
            if ((unsigned)th >= (unsigned)NDIM) continue;
            const float vdh = v * wd[dd] * wh[hh];
            const int rowbase = (td * NDIM + th) * NDIM;
            #pragma unroll
            for (int wi = 0; wi < 2; ++wi) {
                const int tw = iw + wi;
                if ((unsigned)tw >= (unsigned)NDIM) continue;
                atomicAdd(o + rowbase + tw, vdh * ww[wi]);
            }
        }
    }
}

extern "C" void kernel_launch(void* const* d_in, const int* in_sizes, int n_in,
                              void* d_out, int out_size, void* d_ws, size_t ws_size,
                              hipStream_t stream) {
    const float* x = (const float*)d_in[0];
    float* out = (float*)d_out;
    float* ws = (float*)d_ws;
    float* slabs = ws + SLABS_OFF;

    dim3 pgrid(128, 7);   // 6 sum planes + 1 out-zero plane

    if (ws_size >= WS_NEEDED_BYTES) {
        prep_kernel<<<pgrid, 256, 0, stream>>>(x, ws, out);
        scatter_tile_kernel<<<dim3(NBATCH * NTILE), NTHR, 0, stream>>>(x, ws, slabs, out);
        gather_tile_kernel<<<dim3(NBATCH * NTILE), NTHR, 0, stream>>>(slabs, out);
    } else {
        prep_kernel<<<pgrid, 256, 0, stream>>>(x, ws, out);
        scatter_direct_kernel<<<dim3(NBATCH * NP / 256), 256, 0, stream>>>(x, ws, out);
    }
}